// Round 1
// baseline (574.840 us; speedup 1.0000x reference)
//
#include <hip/hip_runtime.h>

// Problem: N=1048576, D_IN=48, D_ATT=8
//   k=x@Wk^T, q=x@Wq^T, v=x@Wv^T
//   S = (q^T k)/sqrt(8)  [8x8], attn=softmax(S, axis=1)
//   out = (v @ attn) @ Wo^T
// Algebra: S = Wq G Wk^T / sqrt(8) with G = x^T x  [48x48]
//          out = x @ M with M = Wv^T attn Wo^T      [48x48]

#define DI 48

// ---------------- K1: G = x^T x ----------------
// grid 512 x 256. Each lane owns a 6x12 block of G (a in 0..7 -> rows 6a..,
// b in 0..3 -> cols 12b..). 32-lane group processes one row at a time;
// two groups per wave, 4 waves -> 8 row-streams per 128-row LDS tile.
constexpr int K1_BLOCKS = 512;
constexpr int TILE_ROWS = 128;
constexpr int LDS_STRIDE = 52;  // dwords; 208B row stride keeps 16B alignment

__global__ __launch_bounds__(256) void k_gram(const float* __restrict__ x,
                                              float* __restrict__ G, int N) {
  __shared__ float lds[9216];  // max(128*52=6656 tile, 4*32*72=9216 reduce)
  const int tid  = threadIdx.x;
  const int wave = tid >> 6;
  const int lane = tid & 63;
  const int g    = lane >> 5;
  const int l32  = lane & 31;
  const int b    = l32 >> 3;  // 0..3  -> j0 = 12b
  const int a    = l32 & 7;   // 0..7  -> i0 = 6a
  const int stream = wave * 2 + g;  // 0..7

  float acc[6][12];
#pragma unroll
  for (int ii = 0; ii < 6; ++ii)
#pragma unroll
    for (int jj = 0; jj < 12; ++jj) acc[ii][jj] = 0.f;

  const int rowsPerBlock = N / K1_BLOCKS;  // 2048
  const long long base = (long long)blockIdx.x * rowsPerBlock;

  for (int t0 = 0; t0 < rowsPerBlock; t0 += TILE_ROWS) {
    // ---- stage 128 rows coalesced: 1536 float4, 6 per thread ----
    const float4* gx = (const float4*)(x + (base + t0) * DI);
#pragma unroll
    for (int k = 0; k < 6; ++k) {
      int f = tid + 256 * k;          // 0..1535
      int row = f / 12, c = f % 12;   // 12 float4 per row
      float4 v = gx[f];
      *(float4*)&lds[row * LDS_STRIDE + c * 4] = v;
    }
    __syncthreads();

    // ---- compute: each 32-lane group walks rows stream, stream+8, ... ----
#pragma unroll 4
    for (int k = 0; k < TILE_ROWS / 8; ++k) {
      const float* rowp = &lds[(stream + 8 * k) * LDS_STRIDE];
      float xi[6], xj[12];
      const float2* pi = (const float2*)(rowp + 6 * a);
      float2 i0 = pi[0], i1 = pi[1], i2 = pi[2];
      xi[0] = i0.x; xi[1] = i0.y; xi[2] = i1.x;
      xi[3] = i1.y; xi[4] = i2.x; xi[5] = i2.y;
      const float4* pj = (const float4*)(rowp + 12 * b);
      float4 j0 = pj[0], j1 = pj[1], j2 = pj[2];
      xj[0] = j0.x; xj[1] = j0.y; xj[2]  = j0.z; xj[3]  = j0.w;
      xj[4] = j1.x; xj[5] = j1.y; xj[6]  = j1.z; xj[7]  = j1.w;
      xj[8] = j2.x; xj[9] = j2.y; xj[10] = j2.z; xj[11] = j2.w;
#pragma unroll
      for (int ii = 0; ii < 6; ++ii)
#pragma unroll
        for (int jj = 0; jj < 12; ++jj) acc[ii][jj] += xi[ii] * xj[jj];
    }
    __syncthreads();
  }

  // ---- block reduction: g=1 halves into g=0 via shfl ----
#pragma unroll
  for (int ii = 0; ii < 6; ++ii)
#pragma unroll
    for (int jj = 0; jj < 12; ++jj)
      acc[ii][jj] += __shfl_down(acc[ii][jj], 32, 64);

  if (g == 0) {
    float* dst = &lds[(wave * 32 + l32) * 72];
#pragma unroll
    for (int ii = 0; ii < 6; ++ii)
#pragma unroll
      for (int jj = 0; jj < 12; ++jj) dst[ii * 12 + jj] = acc[ii][jj];
  }
  __syncthreads();

  // ---- 2304 elements / 256 threads = 9 each; sum 4 waves; atomic to G ----
#pragma unroll
  for (int e9 = 0; e9 < 9; ++e9) {
    int e = tid * 9 + e9;
    int i = e / 48, j = e % 48;
    int aa = i / 6, ii = i % 6, bb = j / 12, jj = j % 12;
    int l = bb * 8 + aa, idx = ii * 12 + jj;
    float s = lds[l * 72 + idx] + lds[(32 + l) * 72 + idx] +
              lds[(64 + l) * 72 + idx] + lds[(96 + l) * 72 + idx];
    atomicAdd(&G[e], s);
  }
}

// ---------------- K3: tiny epilogue -> M ----------------
__global__ void k_combine(const float* __restrict__ G,
                          const float* __restrict__ Wk,
                          const float* __restrict__ Wq,
                          const float* __restrict__ Wv,
                          const float* __restrict__ Wo,
                          float* __restrict__ M) {
  __shared__ float U[8][48];  // U[q][i] = sum_j G[i][j] Wk[q][j]
  __shared__ float A[8][8];
  __shared__ float P[48][8];  // P[i][q] = sum_p Wv[p][i] A[p][q]
  const int t = threadIdx.x;  // 64 threads

  {
    int q = t & 7, i0 = (t >> 3) * 6;
    for (int di = 0; di < 6; ++di) {
      int i = i0 + di;
      float s = 0.f;
      for (int j = 0; j < 48; ++j) s += G[i * 48 + j] * Wk[q * 48 + j];
      U[q][i] = s;
    }
  }
  __syncthreads();

  // S[p][q] and row-softmax over q
  int p = t >> 3, q = t & 7;
  float s = 0.f;
  for (int i = 0; i < 48; ++i) s += Wq[p * 48 + i] * U[q][i];
  s *= 0.35355339059327373f;  // 1/sqrt(8)
  float m = s;
  for (int d = 1; d < 8; d <<= 1) m = fmaxf(m, __shfl_xor(m, d, 64));
  float e = expf(s - m);
  float den = e;
  for (int d = 1; d < 8; d <<= 1) den += __shfl_xor(den, d, 64);
  A[p][q] = e / den;
  __syncthreads();

  {
    int qq = t & 7, i0 = (t >> 3) * 6;
    for (int di = 0; di < 6; ++di) {
      int i = i0 + di;
      float sp = 0.f;
      for (int pp = 0; pp < 8; ++pp) sp += Wv[pp * 48 + i] * A[pp][qq];
      P[i][qq] = sp;
    }
  }
  __syncthreads();

  // M[i][j] = sum_q P[i][q] Wo[j][q]; 36 outputs per thread
  for (int e36 = 0; e36 < 36; ++e36) {
    int idx = t * 36 + e36;
    int i = idx / 48, j = idx % 48;
    float sm = 0.f;
    for (int qq = 0; qq < 8; ++qq) sm += P[i][qq] * Wo[j * 8 + qq];
    M[idx] = sm;
  }
}

// ---------------- K4: out = x @ M ----------------
// One row per thread. M is wave-uniform -> scalar loads + v_fma with SGPR src.
__global__ __launch_bounds__(256) void k_out(const float* __restrict__ x,
                                             const float* __restrict__ M,
                                             float* __restrict__ out, int N) {
  long long r = (long long)blockIdx.x * 256 + threadIdx.x;
  if (r >= N) return;
  const float* xr = x + r * DI;
  float xv[48];
#pragma unroll
  for (int c = 0; c < 12; ++c) {
    float4 v = ((const float4*)xr)[c];
    xv[c * 4 + 0] = v.x; xv[c * 4 + 1] = v.y;
    xv[c * 4 + 2] = v.z; xv[c * 4 + 3] = v.w;
  }
  float acc[48];
#pragma unroll
  for (int j = 0; j < 48; ++j) acc[j] = 0.f;
#pragma unroll
  for (int i = 0; i < 48; ++i) {
    float xi = xv[i];
#pragma unroll
    for (int j = 0; j < 48; ++j) acc[j] += xi * M[i * 48 + j];
  }
  float* orow = out + r * DI;
#pragma unroll
  for (int c = 0; c < 12; ++c) {
    ((float4*)orow)[c] = make_float4(acc[c * 4 + 0], acc[c * 4 + 1],
                                     acc[c * 4 + 2], acc[c * 4 + 3]);
  }
}

extern "C" void kernel_launch(void* const* d_in, const int* in_sizes, int n_in,
                              void* d_out, int out_size, void* d_ws, size_t ws_size,
                              hipStream_t stream) {
  const float* x  = (const float*)d_in[0];
  const float* Wk = (const float*)d_in[1];
  const float* Wq = (const float*)d_in[2];
  const float* Wv = (const float*)d_in[3];
  const float* Wo = (const float*)d_in[4];
  float* out = (float*)d_out;
  const int N = in_sizes[0] / DI;  // 1048576

  float* G = (float*)d_ws;   // 2304 floats
  float* M = G + 2304;       // 2304 floats

  hipMemsetAsync(G, 0, 2304 * sizeof(float), stream);
  k_gram<<<K1_BLOCKS, 256, 0, stream>>>(x, G, N);
  k_combine<<<1, 64, 0, stream>>>(G, Wk, Wq, Wv, Wo, M);
  k_out<<<(N + 255) / 256, 256, 0, stream>>>(x, M, out, N);
}

// Round 2
// 411.373 us; speedup vs baseline: 1.3974x; 1.3974x over previous
//
#include <hip/hip_runtime.h>
#include <hip/hip_bf16.h>

// N=1048576, D_IN=48, D_ATT=8
// Algebra: scores = Wq G Wk^T/sqrt(8), G = x^T x  [48x48]
//          out = x @ M, M = Wv^T softmax(scores) Wo^T  [48x48]
// Pass 1 (k_gram): G via bf16 MFMA (error << 2.8e-2 threshold; softmax saturated).
// Pass 2 (k_combine): tiny epilogue -> Mt[48 cols][64 k] bf16, zero-padded K.
// Pass 3 (k_out): out = x*M via bf16 MFMA, B-fragments held in VGPRs.

#define DI 48

typedef __attribute__((ext_vector_type(8))) short short8;   // 8 bf16 = 4 VGPRs
typedef __attribute__((ext_vector_type(4))) float f32x4;

__device__ inline unsigned int pack_bf16(float lo, float hi) {
  __hip_bfloat162 h = __float22bfloat162_rn(make_float2(lo, hi));
  return *reinterpret_cast<unsigned int*>(&h);
}

constexpr int GB = 512;   // blocks for the two big kernels
constexpr int SD = 36;    // dwords per 64-row bf16 column in k_gram LDS (pad vs 32)

// ---------------- K1: G = x^T x (bf16 MFMA, wave-private LDS) ----------------
// 512 blocks x 256 thr. Wave owns 512 contiguous rows = 8 tiles of 64.
// Per tile: stage 64x48 fp32 -> transposed bf16 LDS; 2 k-steps of
// (3 b128 frag loads + 9 mfma). frag[t] (cols 16t..16t+15) serves as BOTH
// A (tile-row) and B (tile-col) operand since A = x^T.
__global__ __launch_bounds__(256) void k_gram(const float* __restrict__ x,
                                              float* __restrict__ G, int N) {
  __shared__ unsigned int sh[4 * DI * SD];  // 27648 B; reused for reduction
  const int tid = threadIdx.x;
  const int wave = tid >> 6, lane = tid & 63;
  unsigned int* xt = &sh[wave * DI * SD];
  const int quad = lane >> 4, m = lane & 15;

  f32x4 acc[3][3] = {};

  const int rows_per_block = N / GB;          // 2048
  const int rows_per_wave = rows_per_block / 4;  // 512
  const long long base0 = (long long)blockIdx.x * rows_per_block + wave * rows_per_wave;

  for (int tile = 0; tile < 8; ++tile) {
    const float* src = x + (base0 + tile * 64) * DI;
    // ---- stage: 384 tasks (32 row-pairs x 12 col-groups), 6 per lane ----
    float4 va[6], vb[6];
    int rp_[6], cg_[6];
#pragma unroll
    for (int s = 0; s < 6; ++s) {
      int task = lane + 64 * s;
      int rp = task / 12, cg = task % 12;
      rp_[s] = rp; cg_[s] = cg;
      const float4* p = (const float4*)(src + (2 * rp) * DI) + cg;
      va[s] = p[0];
      vb[s] = *(const float4*)((const float*)p + DI);
    }
#pragma unroll
    for (int s = 0; s < 6; ++s) {
      int rp = rp_[s], c0 = 4 * cg_[s];
      xt[(c0 + 0) * SD + rp] = pack_bf16(va[s].x, vb[s].x);
      xt[(c0 + 1) * SD + rp] = pack_bf16(va[s].y, vb[s].y);
      xt[(c0 + 2) * SD + rp] = pack_bf16(va[s].z, vb[s].z);
      xt[(c0 + 3) * SD + rp] = pack_bf16(va[s].w, vb[s].w);
    }
    asm volatile("s_waitcnt lgkmcnt(0)" ::: "memory");
    // ---- compute: 2 k-steps of 32 rows ----
#pragma unroll
    for (int kk = 0; kk < 2; ++kk) {
      short8 f[3];
#pragma unroll
      for (int t = 0; t < 3; ++t) {
        int c = 16 * t + m;
        f[t] = *(const short8*)&xt[c * SD + kk * 16 + quad * 4];
      }
#pragma unroll
      for (int i = 0; i < 3; ++i)
#pragma unroll
        for (int j = 0; j < 3; ++j)
          acc[i][j] = __builtin_amdgcn_mfma_f32_16x16x32_bf16(f[i], f[j], acc[i][j], 0, 0, 0);
    }
  }

  // ---- cross-wave reduce through LDS, then 2304 atomics per block ----
  __syncthreads();
  float* red = (float*)sh;
  if (wave >= 2) {
    float* dst = red + (wave - 2) * 2304 + lane * 36;
#pragma unroll
    for (int i = 0; i < 3; ++i)
#pragma unroll
      for (int j = 0; j < 3; ++j)
#pragma unroll
        for (int r = 0; r < 4; ++r) dst[(i * 3 + j) * 4 + r] = acc[i][j][r];
  }
  __syncthreads();
  if (wave < 2) {
    const float* s2 = red + wave * 2304 + lane * 36;
#pragma unroll
    for (int i = 0; i < 3; ++i)
#pragma unroll
      for (int j = 0; j < 3; ++j)
#pragma unroll
        for (int r = 0; r < 4; ++r) acc[i][j][r] += s2[(i * 3 + j) * 4 + r];
  }
  __syncthreads();
  if (wave == 1) {
    float* dst = red + lane * 36;
#pragma unroll
    for (int i = 0; i < 3; ++i)
#pragma unroll
      for (int j = 0; j < 3; ++j)
#pragma unroll
        for (int r = 0; r < 4; ++r) dst[(i * 3 + j) * 4 + r] = acc[i][j][r];
  }
  __syncthreads();
  if (wave == 0) {
    const float* s1 = red + lane * 36;
#pragma unroll
    for (int i = 0; i < 3; ++i)
#pragma unroll
      for (int j = 0; j < 3; ++j)
#pragma unroll
        for (int r = 0; r < 4; ++r) {
          float v = acc[i][j][r] + s1[(i * 3 + j) * 4 + r];
          atomicAdd(&G[(16 * i + quad * 4 + r) * 48 + 16 * j + m], v);
        }
  }
}

// ---------------- K2: epilogue -> Mt[48][64] bf16 (k-major, zero-padded) ----
__global__ void k_combine(const float* __restrict__ G,
                          const float* __restrict__ Wk,
                          const float* __restrict__ Wq,
                          const float* __restrict__ Wv,
                          const float* __restrict__ Wo,
                          __hip_bfloat16* __restrict__ Mt) {
  __shared__ float sG[2304];
  __shared__ float sWk[384], sWq[384], sWv[384], sWo[384];
  __shared__ float sU[384];  // U[q][i] = sum_j G[i][j] Wk[q][j] -> q*48+i
  __shared__ float sA[64];   // softmax(S)
  __shared__ float sP[384];  // P[i][q] = sum_p Wv[p][i] A[p][q] -> i*8+q
  const int t = threadIdx.x;  // 256

  for (int i = t; i < 2304; i += 256) sG[i] = G[i];
  for (int i = t; i < 384; i += 256) {
    sWk[i] = Wk[i]; sWq[i] = Wq[i]; sWv[i] = Wv[i]; sWo[i] = Wo[i];
  }
  __syncthreads();

  for (int e = t; e < 384; e += 256) {
    int q = e & 7, i = e >> 3;
    float s = 0.f;
#pragma unroll
    for (int j = 0; j < 48; ++j) s += sG[i * 48 + j] * sWk[q * 48 + j];
    sU[q * 48 + i] = s;
  }
  __syncthreads();

  if (t < 64) {  // wave 0: S[p][q] + row softmax over q
    int p = t >> 3, q = t & 7; (void)q;
    float s = 0.f;
#pragma unroll
    for (int i = 0; i < 48; ++i) s += sWq[p * 48 + i] * sU[(t & 7) * 48 + i];
    s *= 0.35355339059327373f;
    float mx = s;
    for (int d = 1; d < 8; d <<= 1) mx = fmaxf(mx, __shfl_xor(mx, d));
    float e = expf(s - mx);
    float den = e;
    for (int d = 1; d < 8; d <<= 1) den += __shfl_xor(den, d);
    sA[t] = e / den;
  }
  __syncthreads();

  for (int e = t; e < 384; e += 256) {
    int q = e & 7, i = e >> 3;
    float s = 0.f;
#pragma unroll
    for (int p = 0; p < 8; ++p) s += sWv[p * 48 + i] * sA[p * 8 + q];
    sP[i * 8 + q] = s;
  }
  __syncthreads();

  // Mt[n][k] = M[k][n] = sum_q P[k][q] Wo[n*8+q]; k in [48,64) -> 0
  for (int e = t; e < 3072; e += 256) {
    int n = e >> 6, k = e & 63;
    float s = 0.f;
    if (k < 48) {
#pragma unroll
      for (int q = 0; q < 8; ++q) s += sP[k * 8 + q] * sWo[n * 8 + q];
    }
    Mt[e] = __float2bfloat16(s);
  }
}

// ---------------- K3: out = x @ M (bf16 MFMA) ----------------
// B-fragments (M) loaded once per wave into 24 VGPRs. Wave-private LDS
// holds 64 rows of x as bf16, row stride 36 dwords (72 bf16), K padded to 64.
__global__ __launch_bounds__(256) void k_out(const float* __restrict__ x,
                                             const __hip_bfloat16* __restrict__ Mt,
                                             float* __restrict__ out, int N) {
  __shared__ unsigned int sh[4 * 64 * SD];  // 36864 B
  const int tid = threadIdx.x;
  const int wave = tid >> 6, lane = tid & 63;
  unsigned int* xs = &sh[wave * 64 * SD];
  const int quad = lane >> 4, m = lane & 15;

  // B-fragments from global Mt (tiny, L2-resident)
  short8 bf[2][3];
#pragma unroll
  for (int kk = 0; kk < 2; ++kk)
#pragma unroll
    for (int tn = 0; tn < 3; ++tn) {
      int n = 16 * tn + m;
      bf[kk][tn] = *(const short8*)((const short*)Mt + n * 64 + kk * 32 + quad * 8);
    }

  // zero the K-pad region (bf16 cols 48..63 = dwords 24..31 of each row), once
#pragma unroll
  for (int s = 0; s < 8; ++s) {
    int d = lane + 64 * s;  // 0..511
    xs[(d >> 3) * SD + 24 + (d & 7)] = 0;
  }

  const int rows_per_block = N / GB;             // 2048
  const int rows_per_wave = rows_per_block / 4;  // 512
  const long long base0 = (long long)blockIdx.x * rows_per_block + wave * rows_per_wave;

  for (int tile = 0; tile < 8; ++tile) {
    const long long rowt = base0 + tile * 64;
    const float* src = x + rowt * DI;
    // ---- stage 64 rows row-major bf16: 768 tasks, 12 per lane ----
    float4 v[12];
    int r_[12], cg_[12];
#pragma unroll
    for (int s = 0; s < 12; ++s) {
      int task = lane + 64 * s;
      int r = task / 12, cg = task % 12;
      r_[s] = r; cg_[s] = cg;
      v[s] = *((const float4*)(src + r * DI) + cg);
    }
#pragma unroll
    for (int s = 0; s < 12; ++s) {
      int r = r_[s], cg = cg_[s];
      xs[r * SD + cg * 2]     = pack_bf16(v[s].x, v[s].y);
      xs[r * SD + cg * 2 + 1] = pack_bf16(v[s].z, v[s].w);
    }
    asm volatile("s_waitcnt lgkmcnt(0)" ::: "memory");
    // ---- 4 groups of 16 rows ----
#pragma unroll
    for (int g = 0; g < 4; ++g) {
      f32x4 acc[3] = {};
#pragma unroll
      for (int kk = 0; kk < 2; ++kk) {
        short8 a = *(const short8*)&xs[(g * 16 + m) * SD + kk * 16 + quad * 4];
#pragma unroll
        for (int tn = 0; tn < 3; ++tn)
          acc[tn] = __builtin_amdgcn_mfma_f32_16x16x32_bf16(a, bf[kk][tn], acc[tn], 0, 0, 0);
      }
      float* orow = out + (rowt + g * 16) * DI;
#pragma unroll
      for (int tn = 0; tn < 3; ++tn)
#pragma unroll
        for (int r = 0; r < 4; ++r)
          orow[(quad * 4 + r) * DI + 16 * tn + m] = acc[tn][r];
    }
  }
}

extern "C" void kernel_launch(void* const* d_in, const int* in_sizes, int n_in,
                              void* d_out, int out_size, void* d_ws, size_t ws_size,
                              hipStream_t stream) {
  const float* x  = (const float*)d_in[0];
  const float* Wk = (const float*)d_in[1];
  const float* Wq = (const float*)d_in[2];
  const float* Wv = (const float*)d_in[3];
  const float* Wo = (const float*)d_in[4];
  float* out = (float*)d_out;
  const int N = in_sizes[0] / DI;  // 1048576

  float* G = (float*)d_ws;                                  // 2304 f32 = 9216 B
  __hip_bfloat16* Mt = (__hip_bfloat16*)((char*)d_ws + 9216);  // 48*64 bf16 = 6144 B

  hipMemsetAsync(G, 0, 2304 * sizeof(float), stream);
  k_gram<<<GB, 256, 0, stream>>>(x, G, N);
  k_combine<<<1, 256, 0, stream>>>(G, Wk, Wq, Wv, Wo, Mt);
  k_out<<<GB, 256, 0, stream>>>(x, Mt, out, N);
}